// Round 1
// baseline (841.272 us; speedup 1.0000x reference)
//
#include <hip/hip_runtime.h>

#define NEG_SLOPE 0.2f
#define EPS_ 1e-9f

typedef __attribute__((ext_vector_type(8))) short short8v;
typedef __attribute__((ext_vector_type(4))) float f32x4;

__device__ __forceinline__ float bf2f(unsigned short u) {
    return __uint_as_float(((unsigned)u) << 16);
}
__device__ __forceinline__ unsigned short f2bf(float f) {
    unsigned u = __float_as_uint(f);
    u = u + 0x7FFFu + ((u >> 16) & 1u);   // round-to-nearest-even
    return (unsigned short)(u >> 16);
}

// ------------------- CSR build -------------------
__global__ void hist_kernel(const int* __restrict__ src, int* __restrict__ cnt, int E) {
    int i = blockIdx.x * blockDim.x + threadIdx.x;
    if (i < E) atomicAdd(&cnt[src[i]], 1);
}

__global__ __launch_bounds__(1024) void scan_kernel(const int* __restrict__ cnt,
        int* __restrict__ row_ptr, int* __restrict__ cursor, int n, int total) {
    // single block of 1024 threads; each thread owns a contiguous chunk
    int t = threadIdx.x;
    int per = (n + 1023) >> 10;
    int base = t * per;
    int lsum = 0;
    for (int i = 0; i < per; ++i) {
        int idx = base + i;
        if (idx < n) lsum += cnt[idx];
    }
    __shared__ int wsum[16];
    int lane = t & 63, wid = t >> 6;
    int incl = lsum;
    for (int off = 1; off < 64; off <<= 1) {
        int v = __shfl_up(incl, off);
        if (lane >= off) incl += v;
    }
    if (lane == 63) wsum[wid] = incl;
    __syncthreads();
    if (t < 16) {
        int v = wsum[t];
        int s = v;
        for (int off = 1; off < 16; off <<= 1) {
            int u = __shfl_up(s, off);
            if (t >= off) s += u;
        }
        wsum[t] = s - v;   // exclusive wave-sum prefix
    }
    __syncthreads();
    int run = incl - lsum + wsum[wid];   // exclusive prefix at chunk start
    for (int i = 0; i < per; ++i) {
        int idx = base + i;
        if (idx < n) {
            row_ptr[idx] = run;
            cursor[idx] = run;
            run += cnt[idx];
        }
    }
    if (t == 0) row_ptr[n] = total;
}

__global__ void scatter_kernel(const int* __restrict__ src, const int* __restrict__ dst,
        int* __restrict__ cursor, int* __restrict__ colv, int E) {
    int i = blockIdx.x * blockDim.x + threadIdx.x;
    if (i < E) {
        int p = atomicAdd(&cursor[src[i]], 1);
        colv[p] = dst[i];
    }
}

// ------------------- W transpose + bf16 convert -------------------
__global__ void wt_kernel(const float* __restrict__ W, short* __restrict__ Wt) {
    int nn = blockIdx.x, k = threadIdx.x;
    Wt[nn * 256 + k] = (short)f2bf(W[k * 256 + nn]);   // Wt[n][k] = W[k][n]
}

// ------------------- GEMM: h' = h @ W  (bf16 MFMA, out bf16) -------------------
// block = 256 thr (4 waves), tile 64 rows x 256 cols, K=256 in chunks of 32
template<bool IN_BF16>
__global__ __launch_bounds__(256) void gemm_kernel(const void* __restrict__ hin,
        const short* __restrict__ Wt, short* __restrict__ hp, int M) {
    __shared__ short As[64 * 40];    // 64 rows x 32 k, pad to 40
    __shared__ short Bt[256 * 40];   // 256 n-rows x 32 k, pad to 40
    int tid = threadIdx.x;
    int lane = tid & 63, w = tid >> 6;
    int m0 = blockIdx.x * 64;

    f32x4 acc[16];
#pragma unroll
    for (int t = 0; t < 16; ++t) acc[t] = (f32x4){0.f, 0.f, 0.f, 0.f};

    int ar = tid >> 2;          // 0..63
    int ac = (tid & 3) * 8;     // 0,8,16,24
    int agrow = m0 + ar;

    for (int kk = 0; kk < 256; kk += 32) {
        // stage A chunk (convert f32->bf16 if needed)
        short8v av = (short8v){0,0,0,0,0,0,0,0};
        if constexpr (IN_BF16) {
            if (agrow < M)
                av = *(const short8v*)((const short*)hin + (size_t)agrow * 256 + kk + ac);
        } else {
            if (agrow < M) {
                const float* s = (const float*)hin + (size_t)agrow * 256 + kk + ac;
                float4 v0 = *(const float4*)s;
                float4 v1 = *(const float4*)(s + 4);
                av[0] = (short)f2bf(v0.x); av[1] = (short)f2bf(v0.y);
                av[2] = (short)f2bf(v0.z); av[3] = (short)f2bf(v0.w);
                av[4] = (short)f2bf(v1.x); av[5] = (short)f2bf(v1.y);
                av[6] = (short)f2bf(v1.z); av[7] = (short)f2bf(v1.w);
            }
        }
        *(short8v*)&As[ar * 40 + ac] = av;
        // stage B chunk from pre-transposed Wt (bf16 copy)
        {
            const short* s = Wt + (size_t)tid * 256 + kk;
#pragma unroll
            for (int i = 0; i < 4; ++i)
                *(short8v*)&Bt[tid * 40 + i * 8] = *(const short8v*)(s + i * 8);
        }
        __syncthreads();
        short8v a = *(const short8v*)&As[(16 * w + (lane & 15)) * 40 + (lane >> 4) * 8];
#pragma unroll
        for (int t = 0; t < 16; ++t) {
            short8v b = *(const short8v*)&Bt[(16 * t + (lane & 15)) * 40 + (lane >> 4) * 8];
            acc[t] = __builtin_amdgcn_mfma_f32_16x16x32_bf16(a, b, acc[t], 0, 0, 0);
        }
        __syncthreads();
    }
    // epilogue: C/D layout col=lane&15, row=(lane>>4)*4+j
    int r0 = 16 * w + (lane >> 4) * 4;
    int c0 = lane & 15;
#pragma unroll
    for (int t = 0; t < 16; ++t) {
#pragma unroll
        for (int j = 0; j < 4; ++j) {
            int grow = m0 + r0 + j;
            if (grow < M) hp[(size_t)grow * 256 + 16 * t + c0] = (short)f2bf(acc[t][j]);
        }
    }
}

// ------------------- alpha_src / alpha_dst -------------------
__global__ __launch_bounds__(256) void alpha_kernel(const unsigned short* __restrict__ hp,
        const float* __restrict__ a, float* __restrict__ asrc, float* __restrict__ adst, int M) {
    int gw = (blockIdx.x * blockDim.x + threadIdx.x) >> 6;
    int lane = threadIdx.x & 63;
    if (gw >= M) return;
    ushort4 hv = *(const ushort4*)(hp + (size_t)gw * 256 + lane * 4);
    float h0 = bf2f(hv.x), h1 = bf2f(hv.y), h2 = bf2f(hv.z), h3 = bf2f(hv.w);
    float4 a0 = *(const float4*)(a + lane * 4);
    float4 a1 = *(const float4*)(a + 256 + lane * 4);
    float s0 = h0 * a0.x + h1 * a0.y + h2 * a0.z + h3 * a0.w;
    float s1 = h0 * a1.x + h1 * a1.y + h2 * a1.z + h3 * a1.w;
    for (int off = 32; off > 0; off >>= 1) {
        s0 += __shfl_xor(s0, off);
        s1 += __shfl_xor(s1, off);
    }
    if (lane == 0) { asrc[gw] = s0; adst[gw] = s1; }
}

// ------------------- aggregation: one wave per node -------------------
template<bool OUT_BF16>
__global__ __launch_bounds__(256) void aggregate_kernel(const int* __restrict__ row_ptr,
        const int* __restrict__ colv, const float* __restrict__ asrc,
        const float* __restrict__ adst, const unsigned short* __restrict__ hp,
        void* __restrict__ outp, int n) {
    int node = (blockIdx.x * blockDim.x + threadIdx.x) >> 6;
    int lane = threadIdx.x & 63;
    if (node >= n) return;
    int beg = row_ptr[node], end = row_ptr[node + 1];
    float ai = asrc[node];
    float acc0 = 0.f, acc1 = 0.f, acc2 = 0.f, acc3 = 0.f, rs = 0.f;
    for (int cur = beg; cur < end; cur += 64) {
        int cnt = min(64, end - cur);
        int j = 0;
        float wgt = 0.f;
        if (lane < cnt) {
            j = colv[cur + lane];
            float x = ai + adst[j];
            float lr = x > 0.f ? x : NEG_SLOPE * x;
            wgt = __expf(-lr);
        }
        for (int k = 0; k < cnt; ++k) {
            int jk = __shfl(j, k);
            float wk = __shfl(wgt, k);
            ushort4 hv = *(const ushort4*)(hp + (size_t)jk * 256 + lane * 4);
            acc0 += wk * bf2f(hv.x);
            acc1 += wk * bf2f(hv.y);
            acc2 += wk * bf2f(hv.z);
            acc3 += wk * bf2f(hv.w);
            rs += wk;
        }
    }
    float inv = 1.f / (rs + EPS_);
    float v0 = acc0 * inv, v1 = acc1 * inv, v2 = acc2 * inv, v3 = acc3 * inv;
    v0 = v0 > 0.f ? v0 : __expf(v0) - 1.f;
    v1 = v1 > 0.f ? v1 : __expf(v1) - 1.f;
    v2 = v2 > 0.f ? v2 : __expf(v2) - 1.f;
    v3 = v3 > 0.f ? v3 : __expf(v3) - 1.f;
    if constexpr (OUT_BF16) {
        ushort4 o;
        o.x = f2bf(v0); o.y = f2bf(v1); o.z = f2bf(v2); o.w = f2bf(v3);
        *(ushort4*)((unsigned short*)outp + (size_t)node * 256 + lane * 4) = o;
    } else {
        float4 o = {v0, v1, v2, v3};
        *(float4*)((float*)outp + (size_t)node * 256 + lane * 4) = o;
    }
}

extern "C" void kernel_launch(void* const* d_in, const int* in_sizes, int n_in,
                              void* d_out, int out_size, void* d_ws, size_t ws_size,
                              hipStream_t stream) {
    const float* sr_emb = (const float*)d_in[0];
    const float* tg_emb = (const float*)d_in[1];
    const float* W1 = (const float*)d_in[2];
    const float* a1 = (const float*)d_in[3];
    const float* W2 = (const float*)d_in[4];
    const float* a2 = (const float*)d_in[5];
    const int* adj_sr = (const int*)d_in[6];
    const int* adj_tg = (const int*)d_in[7];
    int N = in_sizes[0] / 256;
    int E = in_sizes[6] / 2;

    char* p = (char*)d_ws;
    auto alloc = [&](size_t bytes) -> void* {
        void* r = (void*)p;
        p += (bytes + 255) & ~(size_t)255;
        return r;
    };
    int* cnt      = (int*)alloc((size_t)N * 4);
    int* row_ptr  = (int*)alloc((size_t)(N + 1) * 4);
    int* cursor   = (int*)alloc((size_t)N * 4);
    int* colv     = (int*)alloc((size_t)E * 4);
    short* Wt1    = (short*)alloc(256 * 256 * 2);
    short* Wt2    = (short*)alloc(256 * 256 * 2);
    short* hp     = (short*)alloc((size_t)N * 256 * 2);
    float* asrc   = (float*)alloc((size_t)N * 4);
    float* adst   = (float*)alloc((size_t)N * 4);
    short* tmp    = (short*)alloc((size_t)N * 256 * 2);

    wt_kernel<<<256, 256, 0, stream>>>(W1, Wt1);
    wt_kernel<<<256, 256, 0, stream>>>(W2, Wt2);

    int gemm_grid = (N + 63) / 64;
    int nw_grid = (N + 3) / 4;      // one wave per node, 4 waves/block
    int e_grid = (E + 255) / 256;

    for (int g = 0; g < 2; ++g) {
        const int* srcv = (g == 0 ? adj_sr : adj_tg);
        const int* dstv = srcv + E;
        const float* emb = (g == 0 ? sr_emb : tg_emb);
        float* outg = (float*)d_out + (size_t)g * N * 256;

        hipMemsetAsync(cnt, 0, (size_t)N * 4, stream);
        hist_kernel<<<e_grid, 256, 0, stream>>>(srcv, cnt, E);
        scan_kernel<<<1, 1024, 0, stream>>>(cnt, row_ptr, cursor, N, E);
        scatter_kernel<<<e_grid, 256, 0, stream>>>(srcv, dstv, cursor, colv, E);

        // layer 1: f32 input -> bf16 tmp
        gemm_kernel<false><<<gemm_grid, 256, 0, stream>>>(emb, Wt1, hp, N);
        alpha_kernel<<<nw_grid, 256, 0, stream>>>((const unsigned short*)hp, a1, asrc, adst, N);
        aggregate_kernel<true><<<nw_grid, 256, 0, stream>>>(row_ptr, colv, asrc, adst,
                (const unsigned short*)hp, tmp, N);
        // layer 2: bf16 input -> f32 out
        gemm_kernel<true><<<gemm_grid, 256, 0, stream>>>(tmp, Wt2, hp, N);
        alpha_kernel<<<nw_grid, 256, 0, stream>>>((const unsigned short*)hp, a2, asrc, adst, N);
        aggregate_kernel<false><<<nw_grid, 256, 0, stream>>>(row_ptr, colv, asrc, adst,
                (const unsigned short*)hp, outg, N);
    }
}

// Round 2
// 606.551 us; speedup vs baseline: 1.3870x; 1.3870x over previous
//
#include <hip/hip_runtime.h>

#define NEG_SLOPE 0.2f
#define EPS_ 1e-9f

typedef __attribute__((ext_vector_type(8))) short short8v;
typedef __attribute__((ext_vector_type(4))) float f32x4;

__device__ __forceinline__ float bf2f(unsigned short u) {
    return __uint_as_float(((unsigned)u) << 16);
}
__device__ __forceinline__ unsigned short f2bf(float f) {
    unsigned u = __float_as_uint(f);
    u = u + 0x7FFFu + ((u >> 16) & 1u);   // round-to-nearest-even
    return (unsigned short)(u >> 16);
}

// ------------------- CSR build -------------------
__global__ void hist_kernel(const int* __restrict__ src, int* __restrict__ cnt, int E) {
    int i = blockIdx.x * blockDim.x + threadIdx.x;
    if (i < E) atomicAdd(&cnt[src[i]], 1);
}

// Phase 1: per-block (1024 elems, 256 thr x 4) local exclusive prefix + block sum
__global__ __launch_bounds__(256) void scan1_kernel(const int* __restrict__ cnt,
        int* __restrict__ locpre, int* __restrict__ blocksum, int n) {
    int t = threadIdx.x;
    int lane = t & 63, wid = t >> 6;
    int base = blockIdx.x * 1024 + t * 4;
    int4 v = {0, 0, 0, 0};
    if (base + 3 < n) {
        v = *(const int4*)(cnt + base);
    } else {
        if (base + 0 < n) v.x = cnt[base + 0];
        if (base + 1 < n) v.y = cnt[base + 1];
        if (base + 2 < n) v.z = cnt[base + 2];
        if (base + 3 < n) v.w = cnt[base + 3];
    }
    int s = v.x + v.y + v.z + v.w;
    int incl = s;
    for (int off = 1; off < 64; off <<= 1) {
        int u = __shfl_up(incl, off);
        if (lane >= off) incl += u;
    }
    __shared__ int ws[4];
    if (lane == 63) ws[wid] = incl;
    __syncthreads();
    int woff = 0;
    for (int i = 0; i < wid; ++i) woff += ws[i];
    int excl = incl - s + woff;
    int4 o;
    o.x = excl; o.y = excl + v.x; o.z = o.y + v.y; o.w = o.z + v.z;
    if (base + 3 < n) {
        *(int4*)(locpre + base) = o;
    } else {
        if (base + 0 < n) locpre[base + 0] = o.x;
        if (base + 1 < n) locpre[base + 1] = o.y;
        if (base + 2 < n) locpre[base + 2] = o.z;
        if (base + 3 < n) locpre[base + 3] = o.w;
    }
    if (t == 255) blocksum[blockIdx.x] = excl + s;   // block total
}

// Phase 2: single-wave exclusive scan of block sums (nb up to a few thousand)
__global__ __launch_bounds__(64) void scan2_kernel(int* __restrict__ blocksum, int nb) {
    int lane = threadIdx.x;
    int carry = 0;
    for (int base = 0; base < nb; base += 64) {
        int v = (base + lane < nb) ? blocksum[base + lane] : 0;
        int incl = v;
        for (int off = 1; off < 64; off <<= 1) {
            int u = __shfl_up(incl, off);
            if (lane >= off) incl += u;
        }
        int tot = __shfl(incl, 63);
        if (base + lane < nb) blocksum[base + lane] = incl - v + carry;
        carry += tot;
    }
}

// Phase 3: add block offsets, write row_ptr + cursor
__global__ __launch_bounds__(256) void scan3_kernel(const int* __restrict__ locpre,
        const int* __restrict__ blocksum, int* __restrict__ row_ptr,
        int* __restrict__ cursor, int n, int total) {
    int base = blockIdx.x * 1024 + threadIdx.x * 4;
    int off = blocksum[blockIdx.x];
    if (base + 3 < n) {
        int4 v = *(const int4*)(locpre + base);
        v.x += off; v.y += off; v.z += off; v.w += off;
        *(int4*)(row_ptr + base) = v;
        *(int4*)(cursor + base) = v;
    } else {
        for (int i = 0; i < 4; ++i) {
            if (base + i < n) {
                int v = locpre[base + i] + off;
                row_ptr[base + i] = v;
                cursor[base + i] = v;
            }
        }
    }
    if (blockIdx.x == 0 && threadIdx.x == 0) row_ptr[n] = total;
}

__global__ void scatter_kernel(const int* __restrict__ src, const int* __restrict__ dst,
        int* __restrict__ cursor, int* __restrict__ colv, int E) {
    int i = blockIdx.x * blockDim.x + threadIdx.x;
    if (i < E) {
        int p = atomicAdd(&cursor[src[i]], 1);
        colv[p] = dst[i];
    }
}

// ------------------- W transpose + bf16 convert -------------------
__global__ void wt_kernel(const float* __restrict__ W, short* __restrict__ Wt) {
    int nn = blockIdx.x, k = threadIdx.x;
    Wt[nn * 256 + k] = (short)f2bf(W[k * 256 + nn]);   // Wt[n][k] = W[k][n]
}

// ------------------- GEMM: h' = h @ W  (bf16 MFMA, out bf16) -------------------
template<bool IN_BF16>
__global__ __launch_bounds__(256) void gemm_kernel(const void* __restrict__ hin,
        const short* __restrict__ Wt, short* __restrict__ hp, int M) {
    __shared__ short As[64 * 40];    // 64 rows x 32 k, pad to 40
    __shared__ short Bt[256 * 40];   // 256 n-rows x 32 k, pad to 40
    int tid = threadIdx.x;
    int lane = tid & 63, w = tid >> 6;
    int m0 = blockIdx.x * 64;

    f32x4 acc[16];
#pragma unroll
    for (int t = 0; t < 16; ++t) acc[t] = (f32x4){0.f, 0.f, 0.f, 0.f};

    int ar = tid >> 2;          // 0..63
    int ac = (tid & 3) * 8;     // 0,8,16,24
    int agrow = m0 + ar;

    for (int kk = 0; kk < 256; kk += 32) {
        short8v av = (short8v){0,0,0,0,0,0,0,0};
        if constexpr (IN_BF16) {
            if (agrow < M)
                av = *(const short8v*)((const short*)hin + (size_t)agrow * 256 + kk + ac);
        } else {
            if (agrow < M) {
                const float* s = (const float*)hin + (size_t)agrow * 256 + kk + ac;
                float4 v0 = *(const float4*)s;
                float4 v1 = *(const float4*)(s + 4);
                av[0] = (short)f2bf(v0.x); av[1] = (short)f2bf(v0.y);
                av[2] = (short)f2bf(v0.z); av[3] = (short)f2bf(v0.w);
                av[4] = (short)f2bf(v1.x); av[5] = (short)f2bf(v1.y);
                av[6] = (short)f2bf(v1.z); av[7] = (short)f2bf(v1.w);
            }
        }
        *(short8v*)&As[ar * 40 + ac] = av;
        {
            const short* s = Wt + (size_t)tid * 256 + kk;
#pragma unroll
            for (int i = 0; i < 4; ++i)
                *(short8v*)&Bt[tid * 40 + i * 8] = *(const short8v*)(s + i * 8);
        }
        __syncthreads();
        short8v a = *(const short8v*)&As[(16 * w + (lane & 15)) * 40 + (lane >> 4) * 8];
#pragma unroll
        for (int t = 0; t < 16; ++t) {
            short8v b = *(const short8v*)&Bt[(16 * t + (lane & 15)) * 40 + (lane >> 4) * 8];
            acc[t] = __builtin_amdgcn_mfma_f32_16x16x32_bf16(a, b, acc[t], 0, 0, 0);
        }
        __syncthreads();
    }
    int r0 = 16 * w + (lane >> 4) * 4;
    int c0 = lane & 15;
#pragma unroll
    for (int t = 0; t < 16; ++t) {
#pragma unroll
        for (int j = 0; j < 4; ++j) {
            int grow = m0 + r0 + j;
            if (grow < M) hp[(size_t)grow * 256 + 16 * t + c0] = (short)f2bf(acc[t][j]);
        }
    }
}

// ------------------- alpha_src / alpha_dst -------------------
__global__ __launch_bounds__(256) void alpha_kernel(const unsigned short* __restrict__ hp,
        const float* __restrict__ a, float* __restrict__ asrc, float* __restrict__ adst, int M) {
    int gw = (blockIdx.x * blockDim.x + threadIdx.x) >> 6;
    int lane = threadIdx.x & 63;
    if (gw >= M) return;
    ushort4 hv = *(const ushort4*)(hp + (size_t)gw * 256 + lane * 4);
    float h0 = bf2f(hv.x), h1 = bf2f(hv.y), h2 = bf2f(hv.z), h3 = bf2f(hv.w);
    float4 a0 = *(const float4*)(a + lane * 4);
    float4 a1 = *(const float4*)(a + 256 + lane * 4);
    float s0 = h0 * a0.x + h1 * a0.y + h2 * a0.z + h3 * a0.w;
    float s1 = h0 * a1.x + h1 * a1.y + h2 * a1.z + h3 * a1.w;
    for (int off = 32; off > 0; off >>= 1) {
        s0 += __shfl_xor(s0, off);
        s1 += __shfl_xor(s1, off);
    }
    if (lane == 0) { asrc[gw] = s0; adst[gw] = s1; }
}

// ------------------- aggregation: one wave per node -------------------
template<bool OUT_BF16>
__global__ __launch_bounds__(256) void aggregate_kernel(const int* __restrict__ row_ptr,
        const int* __restrict__ colv, const float* __restrict__ asrc,
        const float* __restrict__ adst, const unsigned short* __restrict__ hp,
        void* __restrict__ outp, int n) {
    int node = (blockIdx.x * blockDim.x + threadIdx.x) >> 6;
    int lane = threadIdx.x & 63;
    if (node >= n) return;
    int beg = row_ptr[node], end = row_ptr[node + 1];
    float ai = asrc[node];
    float acc0 = 0.f, acc1 = 0.f, acc2 = 0.f, acc3 = 0.f, rs = 0.f;
    for (int cur = beg; cur < end; cur += 64) {
        int cnt = min(64, end - cur);
        int j = 0;
        float wgt = 0.f;
        if (lane < cnt) {
            j = colv[cur + lane];
            float x = ai + adst[j];
            float lr = x > 0.f ? x : NEG_SLOPE * x;
            wgt = __expf(-lr);
        }
        for (int k = 0; k < cnt; ++k) {
            int jk = __shfl(j, k);
            float wk = __shfl(wgt, k);
            ushort4 hv = *(const ushort4*)(hp + (size_t)jk * 256 + lane * 4);
            acc0 += wk * bf2f(hv.x);
            acc1 += wk * bf2f(hv.y);
            acc2 += wk * bf2f(hv.z);
            acc3 += wk * bf2f(hv.w);
            rs += wk;
        }
    }
    float inv = 1.f / (rs + EPS_);
    float v0 = acc0 * inv, v1 = acc1 * inv, v2 = acc2 * inv, v3 = acc3 * inv;
    v0 = v0 > 0.f ? v0 : __expf(v0) - 1.f;
    v1 = v1 > 0.f ? v1 : __expf(v1) - 1.f;
    v2 = v2 > 0.f ? v2 : __expf(v2) - 1.f;
    v3 = v3 > 0.f ? v3 : __expf(v3) - 1.f;
    if constexpr (OUT_BF16) {
        ushort4 o;
        o.x = f2bf(v0); o.y = f2bf(v1); o.z = f2bf(v2); o.w = f2bf(v3);
        *(ushort4*)((unsigned short*)outp + (size_t)node * 256 + lane * 4) = o;
    } else {
        float4 o = {v0, v1, v2, v3};
        *(float4*)((float*)outp + (size_t)node * 256 + lane * 4) = o;
    }
}

extern "C" void kernel_launch(void* const* d_in, const int* in_sizes, int n_in,
                              void* d_out, int out_size, void* d_ws, size_t ws_size,
                              hipStream_t stream) {
    const float* sr_emb = (const float*)d_in[0];
    const float* tg_emb = (const float*)d_in[1];
    const float* W1 = (const float*)d_in[2];
    const float* a1 = (const float*)d_in[3];
    const float* W2 = (const float*)d_in[4];
    const float* a2 = (const float*)d_in[5];
    const int* adj_sr = (const int*)d_in[6];
    const int* adj_tg = (const int*)d_in[7];
    int N = in_sizes[0] / 256;
    int E = in_sizes[6] / 2;

    char* p = (char*)d_ws;
    auto alloc = [&](size_t bytes) -> void* {
        void* r = (void*)p;
        p += (bytes + 255) & ~(size_t)255;
        return r;
    };
    int nb = (N + 1023) / 1024;
    int* cnt      = (int*)alloc((size_t)N * 4);
    int* row_ptr  = (int*)alloc((size_t)(N + 1) * 4);
    int* cursor   = (int*)alloc((size_t)N * 4);
    int* locpre   = (int*)alloc((size_t)N * 4);
    int* blocksum = (int*)alloc((size_t)nb * 4);
    int* colv     = (int*)alloc((size_t)E * 4);
    short* Wt1    = (short*)alloc(256 * 256 * 2);
    short* Wt2    = (short*)alloc(256 * 256 * 2);
    short* hp     = (short*)alloc((size_t)N * 256 * 2);
    float* asrc   = (float*)alloc((size_t)N * 4);
    float* adst   = (float*)alloc((size_t)N * 4);
    short* tmp    = (short*)alloc((size_t)N * 256 * 2);

    wt_kernel<<<256, 256, 0, stream>>>(W1, Wt1);
    wt_kernel<<<256, 256, 0, stream>>>(W2, Wt2);

    int gemm_grid = (N + 63) / 64;
    int nw_grid = (N + 3) / 4;      // one wave per node, 4 waves/block
    int e_grid = (E + 255) / 256;

    for (int g = 0; g < 2; ++g) {
        const int* srcv = (g == 0 ? adj_sr : adj_tg);
        const int* dstv = srcv + E;
        const float* emb = (g == 0 ? sr_emb : tg_emb);
        float* outg = (float*)d_out + (size_t)g * N * 256;

        hipMemsetAsync(cnt, 0, (size_t)N * 4, stream);
        hist_kernel<<<e_grid, 256, 0, stream>>>(srcv, cnt, E);
        scan1_kernel<<<nb, 256, 0, stream>>>(cnt, locpre, blocksum, N);
        scan2_kernel<<<1, 64, 0, stream>>>(blocksum, nb);
        scan3_kernel<<<nb, 256, 0, stream>>>(locpre, blocksum, row_ptr, cursor, N, E);
        scatter_kernel<<<e_grid, 256, 0, stream>>>(srcv, dstv, cursor, colv, E);

        // layer 1: f32 input -> bf16 tmp
        gemm_kernel<false><<<gemm_grid, 256, 0, stream>>>(emb, Wt1, hp, N);
        alpha_kernel<<<nw_grid, 256, 0, stream>>>((const unsigned short*)hp, a1, asrc, adst, N);
        aggregate_kernel<true><<<nw_grid, 256, 0, stream>>>(row_ptr, colv, asrc, adst,
                (const unsigned short*)hp, tmp, N);
        // layer 2: bf16 input -> f32 out
        gemm_kernel<true><<<gemm_grid, 256, 0, stream>>>(tmp, Wt2, hp, N);
        alpha_kernel<<<nw_grid, 256, 0, stream>>>((const unsigned short*)hp, a2, asrc, adst, N);
        aggregate_kernel<false><<<nw_grid, 256, 0, stream>>>(row_ptr, colv, asrc, adst,
                (const unsigned short*)hp, outg, N);
    }
}

// Round 3
// 583.173 us; speedup vs baseline: 1.4426x; 1.0401x over previous
//
#include <hip/hip_runtime.h>

#define NEG_SLOPE 0.2f
#define EPS_ 1e-9f

typedef __attribute__((ext_vector_type(8))) short short8v;
typedef __attribute__((ext_vector_type(4))) float f32x4;

__device__ __forceinline__ float bf2f(unsigned short u) {
    return __uint_as_float(((unsigned)u) << 16);
}
__device__ __forceinline__ unsigned short f2bf(float f) {
    unsigned u = __float_as_uint(f);
    u = u + 0x7FFFu + ((u >> 16) & 1u);   // round-to-nearest-even
    return (unsigned short)(u >> 16);
}

// ------------------- CSR build -------------------
__global__ void hist_kernel(const int* __restrict__ src, int* __restrict__ cnt, int E) {
    int i = blockIdx.x * blockDim.x + threadIdx.x;
    if (i < E) atomicAdd(&cnt[src[i]], 1);
}

// Phase 1: per-block (1024 elems, 256 thr x 4) local exclusive prefix + block sum
__global__ __launch_bounds__(256) void scan1_kernel(const int* __restrict__ cnt,
        int* __restrict__ locpre, int* __restrict__ blocksum, int n) {
    int t = threadIdx.x;
    int lane = t & 63, wid = t >> 6;
    int base = blockIdx.x * 1024 + t * 4;
    int4 v = {0, 0, 0, 0};
    if (base + 3 < n) {
        v = *(const int4*)(cnt + base);
    } else {
        if (base + 0 < n) v.x = cnt[base + 0];
        if (base + 1 < n) v.y = cnt[base + 1];
        if (base + 2 < n) v.z = cnt[base + 2];
        if (base + 3 < n) v.w = cnt[base + 3];
    }
    int s = v.x + v.y + v.z + v.w;
    int incl = s;
    for (int off = 1; off < 64; off <<= 1) {
        int u = __shfl_up(incl, off);
        if (lane >= off) incl += u;
    }
    __shared__ int ws[4];
    if (lane == 63) ws[wid] = incl;
    __syncthreads();
    int woff = 0;
    for (int i = 0; i < wid; ++i) woff += ws[i];
    int excl = incl - s + woff;
    int4 o;
    o.x = excl; o.y = excl + v.x; o.z = o.y + v.y; o.w = o.z + v.z;
    if (base + 3 < n) {
        *(int4*)(locpre + base) = o;
    } else {
        if (base + 0 < n) locpre[base + 0] = o.x;
        if (base + 1 < n) locpre[base + 1] = o.y;
        if (base + 2 < n) locpre[base + 2] = o.z;
        if (base + 3 < n) locpre[base + 3] = o.w;
    }
    if (t == 255) blocksum[blockIdx.x] = excl + s;   // block total
}

// Phase 2: single-wave exclusive scan of block sums
__global__ __launch_bounds__(64) void scan2_kernel(int* __restrict__ blocksum, int nb) {
    int lane = threadIdx.x;
    int carry = 0;
    for (int base = 0; base < nb; base += 64) {
        int v = (base + lane < nb) ? blocksum[base + lane] : 0;
        int incl = v;
        for (int off = 1; off < 64; off <<= 1) {
            int u = __shfl_up(incl, off);
            if (lane >= off) incl += u;
        }
        int tot = __shfl(incl, 63);
        if (base + lane < nb) blocksum[base + lane] = incl - v + carry;
        carry += tot;
    }
}

// Phase 3: add block offsets, write row_ptr + cursor
__global__ __launch_bounds__(256) void scan3_kernel(const int* __restrict__ locpre,
        const int* __restrict__ blocksum, int* __restrict__ row_ptr,
        int* __restrict__ cursor, int n, int total) {
    int base = blockIdx.x * 1024 + threadIdx.x * 4;
    int off = blocksum[blockIdx.x];
    if (base + 3 < n) {
        int4 v = *(const int4*)(locpre + base);
        v.x += off; v.y += off; v.z += off; v.w += off;
        *(int4*)(row_ptr + base) = v;
        *(int4*)(cursor + base) = v;
    } else {
        for (int i = 0; i < 4; ++i) {
            if (base + i < n) {
                int v = locpre[base + i] + off;
                row_ptr[base + i] = v;
                cursor[base + i] = v;
            }
        }
    }
    if (blockIdx.x == 0 && threadIdx.x == 0) row_ptr[n] = total;
}

__global__ void scatter_kernel(const int* __restrict__ src, const int* __restrict__ dst,
        int* __restrict__ cursor, int* __restrict__ colv, int E) {
    int i = blockIdx.x * blockDim.x + threadIdx.x;
    if (i < E) {
        int p = atomicAdd(&cursor[src[i]], 1);
        colv[p] = dst[i];
    }
}

// ------------------- W transpose + bf16 convert -------------------
__global__ void wt_kernel(const float* __restrict__ W, short* __restrict__ Wt) {
    int nn = blockIdx.x, k = threadIdx.x;
    Wt[nn * 256 + k] = (short)f2bf(W[k * 256 + nn]);   // Wt[n][k] = W[k][n]
}

// ------------------- GEMM: h' = h @ W  (bf16 MFMA, out bf16) -------------------
template<bool IN_BF16>
__global__ __launch_bounds__(256) void gemm_kernel(const void* __restrict__ hin,
        const short* __restrict__ Wt, short* __restrict__ hp, int M) {
    __shared__ short As[64 * 40];    // 64 rows x 32 k, pad to 40
    __shared__ short Bt[256 * 40];   // 256 n-rows x 32 k, pad to 40
    int tid = threadIdx.x;
    int lane = tid & 63, w = tid >> 6;
    int m0 = blockIdx.x * 64;

    f32x4 acc[16];
#pragma unroll
    for (int t = 0; t < 16; ++t) acc[t] = (f32x4){0.f, 0.f, 0.f, 0.f};

    int ar = tid >> 2;          // 0..63
    int ac = (tid & 3) * 8;     // 0,8,16,24
    int agrow = m0 + ar;

    for (int kk = 0; kk < 256; kk += 32) {
        short8v av = (short8v){0,0,0,0,0,0,0,0};
        if constexpr (IN_BF16) {
            if (agrow < M)
                av = *(const short8v*)((const short*)hin + (size_t)agrow * 256 + kk + ac);
        } else {
            if (agrow < M) {
                const float* s = (const float*)hin + (size_t)agrow * 256 + kk + ac;
                float4 v0 = *(const float4*)s;
                float4 v1 = *(const float4*)(s + 4);
                av[0] = (short)f2bf(v0.x); av[1] = (short)f2bf(v0.y);
                av[2] = (short)f2bf(v0.z); av[3] = (short)f2bf(v0.w);
                av[4] = (short)f2bf(v1.x); av[5] = (short)f2bf(v1.y);
                av[6] = (short)f2bf(v1.z); av[7] = (short)f2bf(v1.w);
            }
        }
        *(short8v*)&As[ar * 40 + ac] = av;
        {
            const short* s = Wt + (size_t)tid * 256 + kk;
#pragma unroll
            for (int i = 0; i < 4; ++i)
                *(short8v*)&Bt[tid * 40 + i * 8] = *(const short8v*)(s + i * 8);
        }
        __syncthreads();
        short8v a = *(const short8v*)&As[(16 * w + (lane & 15)) * 40 + (lane >> 4) * 8];
#pragma unroll
        for (int t = 0; t < 16; ++t) {
            short8v b = *(const short8v*)&Bt[(16 * t + (lane & 15)) * 40 + (lane >> 4) * 8];
            acc[t] = __builtin_amdgcn_mfma_f32_16x16x32_bf16(a, b, acc[t], 0, 0, 0);
        }
        __syncthreads();
    }
    int r0 = 16 * w + (lane >> 4) * 4;
    int c0 = lane & 15;
#pragma unroll
    for (int t = 0; t < 16; ++t) {
#pragma unroll
        for (int j = 0; j < 4; ++j) {
            int grow = m0 + r0 + j;
            if (grow < M) hp[(size_t)grow * 256 + 16 * t + c0] = (short)f2bf(acc[t][j]);
        }
    }
}

// ------------------- alpha_src / alpha_dst -------------------
__global__ __launch_bounds__(256) void alpha_kernel(const unsigned short* __restrict__ hp,
        const float* __restrict__ a, float* __restrict__ asrc, float* __restrict__ adst, int M) {
    int gw = (blockIdx.x * blockDim.x + threadIdx.x) >> 6;
    int lane = threadIdx.x & 63;
    if (gw >= M) return;
    ushort4 hv = *(const ushort4*)(hp + (size_t)gw * 256 + lane * 4);
    float h0 = bf2f(hv.x), h1 = bf2f(hv.y), h2 = bf2f(hv.z), h3 = bf2f(hv.w);
    float4 a0 = *(const float4*)(a + lane * 4);
    float4 a1 = *(const float4*)(a + 256 + lane * 4);
    float s0 = h0 * a0.x + h1 * a0.y + h2 * a0.z + h3 * a0.w;
    float s1 = h0 * a1.x + h1 * a1.y + h2 * a1.z + h3 * a1.w;
    for (int off = 32; off > 0; off >>= 1) {
        s0 += __shfl_xor(s0, off);
        s1 += __shfl_xor(s1, off);
    }
    if (lane == 0) { asrc[gw] = s0; adst[gw] = s1; }
}

// ------------------- aggregation: one wave per node, 16-deep gather pipeline ----
// LDQ issues the ushort4 row-gather for edge slot kk; CNS consumes it.
// Guards on m are wave-uniform (cnt/k0 uniform) -> scalar branches; the up-to-16
// gathers issue back-to-back so the wave takes ~1 memory stall per 16 edges
// instead of per edge (R2: VGPR=16 showed compiler kept only 1 load in flight).
#define LDQ(q, kk) { int jj = __shfl(j, (kk)); \
    q = *(const ushort4*)(hp + (size_t)jj * 256 + (lane << 2)); }
#define CNS(q, kk) { float wk = __shfl(wgt, (kk)); \
    acc0 = fmaf(wk, bf2f(q.x), acc0); acc1 = fmaf(wk, bf2f(q.y), acc1); \
    acc2 = fmaf(wk, bf2f(q.z), acc2); acc3 = fmaf(wk, bf2f(q.w), acc3); \
    rs += wk; }

template<bool OUT_BF16>
__global__ __launch_bounds__(256) void aggregate_kernel(const int* __restrict__ row_ptr,
        const int* __restrict__ colv, const float* __restrict__ asrc,
        const float* __restrict__ adst, const unsigned short* __restrict__ hp,
        void* __restrict__ outp, int n) {
    int node = (blockIdx.x * blockDim.x + threadIdx.x) >> 6;
    int lane = threadIdx.x & 63;
    if (node >= n) return;
    int beg = row_ptr[node], end = row_ptr[node + 1];
    float ai = asrc[node];
    float acc0 = 0.f, acc1 = 0.f, acc2 = 0.f, acc3 = 0.f, rs = 0.f;
    for (int cur = beg; cur < end; cur += 64) {
        int cnt = min(64, end - cur);
        int j = 0;
        float wgt = 0.f;
        if (lane < cnt) {
            j = colv[cur + lane];
            float x = ai + adst[j];
            float lr = x > 0.f ? x : NEG_SLOPE * x;
            wgt = __expf(-lr);
        }
        for (int k0 = 0; k0 < cnt; k0 += 16) {
            int m = cnt - k0;   // wave-uniform
            ushort4 q0, q1, q2, q3, q4, q5, q6, q7, q8, q9, qa, qb, qc, qd, qe, qf;
            LDQ(q0, k0 + 0);
            if (m > 1)  LDQ(q1, k0 + 1);
            if (m > 2)  LDQ(q2, k0 + 2);
            if (m > 3)  LDQ(q3, k0 + 3);
            if (m > 4)  LDQ(q4, k0 + 4);
            if (m > 5)  LDQ(q5, k0 + 5);
            if (m > 6)  LDQ(q6, k0 + 6);
            if (m > 7)  LDQ(q7, k0 + 7);
            if (m > 8)  LDQ(q8, k0 + 8);
            if (m > 9)  LDQ(q9, k0 + 9);
            if (m > 10) LDQ(qa, k0 + 10);
            if (m > 11) LDQ(qb, k0 + 11);
            if (m > 12) LDQ(qc, k0 + 12);
            if (m > 13) LDQ(qd, k0 + 13);
            if (m > 14) LDQ(qe, k0 + 14);
            if (m > 15) LDQ(qf, k0 + 15);
            CNS(q0, k0 + 0);
            if (m > 1)  CNS(q1, k0 + 1);
            if (m > 2)  CNS(q2, k0 + 2);
            if (m > 3)  CNS(q3, k0 + 3);
            if (m > 4)  CNS(q4, k0 + 4);
            if (m > 5)  CNS(q5, k0 + 5);
            if (m > 6)  CNS(q6, k0 + 6);
            if (m > 7)  CNS(q7, k0 + 7);
            if (m > 8)  CNS(q8, k0 + 8);
            if (m > 9)  CNS(q9, k0 + 9);
            if (m > 10) CNS(qa, k0 + 10);
            if (m > 11) CNS(qb, k0 + 11);
            if (m > 12) CNS(qc, k0 + 12);
            if (m > 13) CNS(qd, k0 + 13);
            if (m > 14) CNS(qe, k0 + 14);
            if (m > 15) CNS(qf, k0 + 15);
        }
    }
    float inv = 1.f / (rs + EPS_);
    float v0 = acc0 * inv, v1 = acc1 * inv, v2 = acc2 * inv, v3 = acc3 * inv;
    v0 = v0 > 0.f ? v0 : __expf(v0) - 1.f;
    v1 = v1 > 0.f ? v1 : __expf(v1) - 1.f;
    v2 = v2 > 0.f ? v2 : __expf(v2) - 1.f;
    v3 = v3 > 0.f ? v3 : __expf(v3) - 1.f;
    if constexpr (OUT_BF16) {
        ushort4 o;
        o.x = f2bf(v0); o.y = f2bf(v1); o.z = f2bf(v2); o.w = f2bf(v3);
        *(ushort4*)((unsigned short*)outp + (size_t)node * 256 + lane * 4) = o;
    } else {
        float4 o = {v0, v1, v2, v3};
        *(float4*)((float*)outp + (size_t)node * 256 + lane * 4) = o;
    }
}

extern "C" void kernel_launch(void* const* d_in, const int* in_sizes, int n_in,
                              void* d_out, int out_size, void* d_ws, size_t ws_size,
                              hipStream_t stream) {
    const float* sr_emb = (const float*)d_in[0];
    const float* tg_emb = (const float*)d_in[1];
    const float* W1 = (const float*)d_in[2];
    const float* a1 = (const float*)d_in[3];
    const float* W2 = (const float*)d_in[4];
    const float* a2 = (const float*)d_in[5];
    const int* adj_sr = (const int*)d_in[6];
    const int* adj_tg = (const int*)d_in[7];
    int N = in_sizes[0] / 256;
    int E = in_sizes[6] / 2;

    char* p = (char*)d_ws;
    auto alloc = [&](size_t bytes) -> void* {
        void* r = (void*)p;
        p += (bytes + 255) & ~(size_t)255;
        return r;
    };
    int nb = (N + 1023) / 1024;
    int* cnt      = (int*)alloc((size_t)N * 4);
    int* row_ptr  = (int*)alloc((size_t)(N + 1) * 4);
    int* cursor   = (int*)alloc((size_t)N * 4);
    int* locpre   = (int*)alloc((size_t)N * 4);
    int* blocksum = (int*)alloc((size_t)nb * 4);
    int* colv     = (int*)alloc((size_t)E * 4);
    short* Wt1    = (short*)alloc(256 * 256 * 2);
    short* Wt2    = (short*)alloc(256 * 256 * 2);
    short* hp     = (short*)alloc((size_t)N * 256 * 2);
    float* asrc   = (float*)alloc((size_t)N * 4);
    float* adst   = (float*)alloc((size_t)N * 4);
    short* tmp    = (short*)alloc((size_t)N * 256 * 2);

    wt_kernel<<<256, 256, 0, stream>>>(W1, Wt1);
    wt_kernel<<<256, 256, 0, stream>>>(W2, Wt2);

    int gemm_grid = (N + 63) / 64;
    int nw_grid = (N + 3) / 4;      // one wave per node, 4 waves/block
    int e_grid = (E + 255) / 256;

    for (int g = 0; g < 2; ++g) {
        const int* srcv = (g == 0 ? adj_sr : adj_tg);
        const int* dstv = srcv + E;
        const float* emb = (g == 0 ? sr_emb : tg_emb);
        float* outg = (float*)d_out + (size_t)g * N * 256;

        hipMemsetAsync(cnt, 0, (size_t)N * 4, stream);
        hist_kernel<<<e_grid, 256, 0, stream>>>(srcv, cnt, E);
        scan1_kernel<<<nb, 256, 0, stream>>>(cnt, locpre, blocksum, N);
        scan2_kernel<<<1, 64, 0, stream>>>(blocksum, nb);
        scan3_kernel<<<nb, 256, 0, stream>>>(locpre, blocksum, row_ptr, cursor, N, E);
        scatter_kernel<<<e_grid, 256, 0, stream>>>(srcv, dstv, cursor, colv, E);

        // layer 1: f32 input -> bf16 tmp
        gemm_kernel<false><<<gemm_grid, 256, 0, stream>>>(emb, Wt1, hp, N);
        alpha_kernel<<<nw_grid, 256, 0, stream>>>((const unsigned short*)hp, a1, asrc, adst, N);
        aggregate_kernel<true><<<nw_grid, 256, 0, stream>>>(row_ptr, colv, asrc, adst,
                (const unsigned short*)hp, tmp, N);
        // layer 2: bf16 input -> f32 out
        gemm_kernel<true><<<gemm_grid, 256, 0, stream>>>(tmp, Wt2, hp, N);
        alpha_kernel<<<nw_grid, 256, 0, stream>>>((const unsigned short*)hp, a2, asrc, adst, N);
        aggregate_kernel<false><<<nw_grid, 256, 0, stream>>>(row_ptr, colv, asrc, adst,
                (const unsigned short*)hp, outg, N);
    }
}